// Round 10
// baseline (544.315 us; speedup 1.0000x reference)
//
#include <hip/hip_runtime.h>
#include <hip/hip_cooperative_groups.h>
#include <math.h>

namespace cg = cooperative_groups;

#define IN_CH 128
#define OUT_CH 16
#define B 256
#define CH 8192           // edges per sort chunk
#define LSH 6             // leaf = node >> 6  (64 nodes per leaf)
#define LNODES 64
#define MAXNL 1024
#define MAXG 256
#define SMEM_U32 7424     // 29696 B LDS arena (sized by place phase)

// ================= shared device phase blocks =================

// exclusive prefix of vals[0..NL) into dst (LDS), B threads, 4 bins/thread
__device__ __forceinline__ void scan_nl(const unsigned* __restrict__ vals, unsigned* dst,
                                        unsigned* sums, int NL) {
    int tid = threadIdx.x;
    int b0 = tid * 4;
    unsigned v[4]; unsigned loc = 0;
#pragma unroll
    for (int q = 0; q < 4; ++q) { int i = b0 + q; v[q] = (i < NL) ? vals[i] : 0u; loc += v[q]; }
    sums[tid] = loc;
    __syncthreads();
    for (int off = 1; off < B; off <<= 1) {
        unsigned a = (tid >= off) ? sums[tid - off] : 0u;
        __syncthreads();
        sums[tid] += a;
        __syncthreads();
    }
    unsigned run = sums[tid] - loc;
#pragma unroll
    for (int q = 0; q < 4; ++q) { int i = b0 + q; if (i < NL) dst[i] = run; run += v[q]; }
    __syncthreads();
}

__device__ void hist_block(int c, unsigned* sm, const int* __restrict__ col,
                           unsigned* __restrict__ bh, int E, int NL) {
    unsigned* hc = sm;
    int tid = threadIdx.x;
    for (int i = tid; i < NL; i += B) hc[i] = 0u;
    __syncthreads();
    int base = c * CH;
    int end = base + CH < E ? base + CH : E;
    for (int e = base + tid; e < end; e += B)
        atomicAdd(&hc[col[e] >> LSH], 1u);
    __syncthreads();
    unsigned* out = bh + (size_t)c * NL;
    for (int i = tid; i < NL; i += B) out[i] = hc[i];
    __syncthreads();
}

__device__ void colscan_block(int j, unsigned* sm, unsigned* __restrict__ bh,
                              unsigned* __restrict__ tot, int G, int NL) {
    unsigned* s = sm;
    int tid = threadIdx.x;
    unsigned carry = 0;
    for (int g0 = 0; g0 < G; g0 += B) {
        __syncthreads();
        int g = g0 + tid;
        unsigned v = (g < G) ? bh[(size_t)g * NL + j] : 0u;
        s[tid] = v;
        __syncthreads();
        for (int off = 1; off < B; off <<= 1) {
            unsigned add = (tid >= off) ? s[tid - off] : 0u;
            __syncthreads();
            s[tid] += add;
            __syncthreads();
        }
        if (g < G) bh[(size_t)g * NL + j] = carry + s[tid] - v;
        carry += s[B - 1];
    }
    if (tid == 0) tot[j] = carry;
    __syncthreads();
}

__device__ void place_block(int c, unsigned* sm, const int* __restrict__ row,
                            const int* __restrict__ col, const float* __restrict__ ew,
                            const unsigned* __restrict__ bh, const unsigned* __restrict__ tot,
                            uint2* __restrict__ rec, int E, int NL) {
    unsigned short* l_idx = (unsigned short*)sm;   // CH u16 = 4096 u32
    unsigned* gbase = sm + CH / 2;
    unsigned* lscan = gbase + MAXNL;
    unsigned* lctr  = lscan + MAXNL;
    unsigned* sums  = lctr + MAXNL;                // 256
    int tid = threadIdx.x;
    int base = c * CH;
    int end = base + CH < E ? base + CH : E;
    int cnt = end - base;

    scan_nl(tot, gbase, sums, NL);                 // global leaf bases
    for (int i = tid; i < NL; i += B) lctr[i] = 0u;
    __syncthreads();
    for (int j = tid; j < cnt; j += B)
        atomicAdd(&lctr[col[base + j] >> LSH], 1u);
    __syncthreads();
    scan_nl(lctr, lscan, sums, NL);                // local chunk bases
    for (int i = tid; i < NL; i += B) lctr[i] = lscan[i];
    __syncthreads();
    for (int j = tid; j < cnt; j += B) {
        int lf = col[base + j] >> LSH;
        unsigned pos = atomicAdd(&lctr[lf], 1u);
        l_idx[pos] = (unsigned short)j;
    }
    __syncthreads();
    const unsigned* myb = bh + (size_t)c * NL;
    for (int j = tid; j < cnt; j += B) {           // run-coalesced 8B record writes
        int e = base + l_idx[j];
        int cc = col[e];
        int lf = cc >> LSH;
        unsigned outp = gbase[lf] + myb[lf] + ((unsigned)j - lscan[lf]);
        rec[outp] = make_uint2(((unsigned)row[e] << 6) | (unsigned)(cc & (LNODES - 1)),
                               __float_as_uint(ew[e]));
    }
    __syncthreads();
}

__device__ void sort2_block(int l, unsigned* sm, const uint2* __restrict__ rec,
                            const unsigned* __restrict__ tot, uint2* __restrict__ rec2,
                            unsigned* __restrict__ nptr, float* __restrict__ dinv,
                            int N, int NL) {
    unsigned* sums  = sm;                  // 256
    unsigned* gbase = sm + B;              // MAXNL
    unsigned* hist  = gbase + MAXNL;       // 64
    float*    dacc  = (float*)(hist + LNODES);
    unsigned* start = hist + 2 * LNODES;
    int tid = threadIdx.x;
    scan_nl(tot, gbase, sums, NL);
    int seg = (int)gbase[l];
    int end = seg + (int)tot[l];
    if (tid < LNODES) { hist[tid] = 0u; dacc[tid] = 0.f; }
    __syncthreads();
    for (int j = seg + tid; j < end; j += B) {
        uint2 u = rec[j];
        int cc = (int)(u.x & (LNODES - 1));
        atomicAdd(&hist[cc], 1u);
        atomicAdd(&dacc[cc], __uint_as_float(u.y));
    }
    __syncthreads();
    if (tid < LNODES) {  // one wave -> shfl scan
        unsigned v = hist[tid];
        unsigned sum = v;
        for (int off = 1; off < LNODES; off <<= 1) {
            unsigned o = __shfl_up(sum, off, 64);
            if (tid >= off) sum += o;
        }
        unsigned st = (unsigned)seg + sum - v;
        start[tid] = st;
        int n = l * LNODES + tid;
        if (n < N) {
            nptr[n] = st;
            dinv[n] = rsqrtf(1.0f + dacc[tid]);
        }
    }
    if (l == NL - 1 && tid == 0) nptr[N] = (unsigned)end;
    __syncthreads();
    for (int j = seg + tid; j < end; j += B) {
        uint2 u = rec[j];
        int cc = (int)(u.x & (LNODES - 1));
        unsigned pos = atomicAdd(&start[cc], 1u);
        rec2[pos] = make_uint2(u.x >> 6, u.y);
    }
    __syncthreads();
}

// projection into g-space: g0 = dinv ⊙ (x @ W^T); grid-stride over 16-row tiles
__device__ void proj_phase(unsigned* sm, const float* __restrict__ x, const float* __restrict__ W,
                           const float* __restrict__ dinv, float* __restrict__ y, int N) {
    float* sW = (float*)sm;                // 16*129 floats
    int tid = threadIdx.x;
    for (int i = tid; i < OUT_CH * IN_CH; i += B) {
        int o = i >> 7, k = i & 127;
        sW[o * (IN_CH + 1) + k] = W[i];
    }
    __syncthreads();
    int nt = (N + 15) / 16;
    for (int tile = blockIdx.x; tile < nt; tile += gridDim.x) {
        int n = tile * 16 + (tid >> 4);
        int o = tid & 15;
        if (n < N) {
            const float* xr = x + (size_t)n * IN_CH;
            const float* wr = sW + o * (IN_CH + 1);
            float acc = 0.0f;
#pragma unroll
            for (int k = 0; k < IN_CH; k += 4) {
                float4 xv = *reinterpret_cast<const float4*>(xr + k);
                acc += xv.x * wr[k] + xv.y * wr[k + 1] + xv.z * wr[k + 2] + xv.w * wr[k + 3];
            }
            y[(size_t)n * OUT_CH + o] = dinv[n] * acc;
        }
    }
    __syncthreads();
}

// CSR hop in g-space: 16 threads/node, register accumulation, no atomics
template <bool FINAL>
__device__ void hop_phase(const uint2* __restrict__ rec2, const unsigned* __restrict__ nptr,
                          const float* __restrict__ dinv, const float* __restrict__ gin,
                          float* __restrict__ out, int N) {
    int total = (N * OUT_CH + B - 1) / B;
    for (int v = blockIdx.x; v < total; v += gridDim.x) {
        int t = v * B + threadIdx.x;
        int n = t >> 4, ch = t & 15;
        if (n >= N) continue;
        int j0 = (int)nptr[n], j1 = (int)nptr[n + 1];
        float acc = 0.f;
        int j = j0;
        for (; j + 3 < j1; j += 4) {  // 4-wide for MLP
            uint2 u0 = rec2[j], u1 = rec2[j + 1], u2 = rec2[j + 2], u3 = rec2[j + 3];
            acc += __uint_as_float(u0.y) * gin[(size_t)u0.x * OUT_CH + ch]
                 + __uint_as_float(u1.y) * gin[(size_t)u1.x * OUT_CH + ch]
                 + __uint_as_float(u2.y) * gin[(size_t)u2.x * OUT_CH + ch]
                 + __uint_as_float(u3.y) * gin[(size_t)u3.x * OUT_CH + ch];
        }
        for (; j < j1; ++j) {
            uint2 u = rec2[j];
            acc += __uint_as_float(u.y) * gin[(size_t)u.x * OUT_CH + ch];
        }
        float d = dinv[n];
        float s = gin[(size_t)n * OUT_CH + ch] + acc;
        if (!FINAL) {
            out[(size_t)n * OUT_CH + ch] = d * d * s;
        } else {
            float vv = d * s;
            float m = vv;
#pragma unroll
            for (int off = 1; off < 16; off <<= 1) m = fmaxf(m, __shfl_xor(m, off, 16));
            float se = expf(vv - m);
#pragma unroll
            for (int off = 1; off < 16; off <<= 1) se += __shfl_xor(se, off, 16);
            out[(size_t)n * OUT_CH + ch] = vv - m - logf(se);
        }
    }
}

// ================= cooperative megakernel =================

struct MegaArgs {
    const int* row; const int* col; const float* ew; const float* x; const float* W;
    unsigned* bh; unsigned* tot; uint2* rec; uint2* rec2; unsigned* nptr;
    float* dinv; float* g0; float* g1; float* out;
    int N, E, G, NL;
};

__global__ void __launch_bounds__(B) mega(MegaArgs a) {
    cg::grid_group gg = cg::this_grid();
    __shared__ unsigned sm[SMEM_U32];
    for (int c = blockIdx.x; c < a.G; c += gridDim.x)
        hist_block(c, sm, a.col, a.bh, a.E, a.NL);
    gg.sync();
    for (int j = blockIdx.x; j < a.NL; j += gridDim.x)
        colscan_block(j, sm, a.bh, a.tot, a.G, a.NL);
    gg.sync();
    for (int c = blockIdx.x; c < a.G; c += gridDim.x)
        place_block(c, sm, a.row, a.col, a.ew, a.bh, a.tot, a.rec, a.E, a.NL);
    gg.sync();
    for (int l = blockIdx.x; l < a.NL; l += gridDim.x)
        sort2_block(l, sm, a.rec, a.tot, a.rec2, a.nptr, a.dinv, a.N, a.NL);
    gg.sync();
    proj_phase(sm, a.x, a.W, a.dinv, a.g0, a.N);
    gg.sync();
    hop_phase<false>(a.rec2, a.nptr, a.dinv, a.g0, a.g1, a.N);
    gg.sync();
    hop_phase<true>(a.rec2, a.nptr, a.dinv, a.g1, a.out, a.N);
}

// ================= standalone kernels (fallback pipeline) =================

__global__ void __launch_bounds__(B) k_hist(const int* col, unsigned* bh, int E, int NL) {
    __shared__ unsigned sm[MAXNL];
    hist_block(blockIdx.x, sm, col, bh, E, NL);
}
__global__ void __launch_bounds__(B) k_colscan(unsigned* bh, unsigned* tot, int G, int NL) {
    __shared__ unsigned sm[B];
    colscan_block(blockIdx.x, sm, bh, tot, G, NL);
}
__global__ void __launch_bounds__(B) k_place(const int* row, const int* col, const float* ew,
                                             const unsigned* bh, const unsigned* tot,
                                             uint2* rec, int E, int NL) {
    __shared__ unsigned sm[SMEM_U32];
    place_block(blockIdx.x, sm, row, col, ew, bh, tot, rec, E, NL);
}
__global__ void __launch_bounds__(B) k_sort2(const uint2* rec, const unsigned* tot, uint2* rec2,
                                             unsigned* nptr, float* dinv, int N, int NL) {
    __shared__ unsigned sm[B + MAXNL + 3 * LNODES];
    sort2_block(blockIdx.x, sm, rec, tot, rec2, nptr, dinv, N, NL);
}
__global__ void __launch_bounds__(B) k_proj(const float* x, const float* W, const float* dinv,
                                            float* y, int N) {
    __shared__ unsigned sm[OUT_CH * (IN_CH + 1)];
    proj_phase(sm, x, W, dinv, y, N);
}
template <bool FINAL>
__global__ void __launch_bounds__(B) k_hop(const uint2* rec2, const unsigned* nptr,
                                           const float* dinv, const float* gin,
                                           float* out, int N) {
    hop_phase<FINAL>(rec2, nptr, dinv, gin, out, N);
}

// ================= ultimate fallback (r2 structure) =================

__global__ void fb_deginit(float* deg, int N) {
    int i = blockIdx.x * blockDim.x + threadIdx.x;
    if (i < N) deg[i] = 1.0f;
}
__global__ void fb_deg(const int* __restrict__ col, const float* __restrict__ ew,
                       float* deg, int E) {
    int e = blockIdx.x * blockDim.x + threadIdx.x;
    if (e < E) atomicAdd(&deg[col[e]], ew[e]);
}
__global__ void fb_dinv(const float* __restrict__ deg, float* dinv, int N) {
    int i = blockIdx.x * blockDim.x + threadIdx.x;
    if (i < N) dinv[i] = rsqrtf(deg[i]);
}
__global__ void fb_proj(const float* __restrict__ x, const float* __restrict__ W,
                        float* __restrict__ y, int N) {
    __shared__ float sW[OUT_CH * (IN_CH + 1)];
    for (int i = threadIdx.x; i < OUT_CH * IN_CH; i += blockDim.x) {
        int o = i >> 7, k = i & 127;
        sW[o * (IN_CH + 1) + k] = W[i];
    }
    __syncthreads();
    int t = threadIdx.x;
    int n = blockIdx.x * 16 + (t >> 4);
    int o = t & 15;
    if (n >= N) return;
    const float* xr = x + (size_t)n * IN_CH;
    const float* wr = sW + o * (IN_CH + 1);
    float acc = 0.0f;
#pragma unroll
    for (int k = 0; k < IN_CH; k += 4) {
        float4 xv = *reinterpret_cast<const float4*>(xr + k);
        acc += xv.x * wr[k] + xv.y * wr[k + 1] + xv.z * wr[k + 2] + xv.w * wr[k + 3];
    }
    y[(size_t)n * OUT_CH + o] = acc;
}
__global__ void fb_selfinit(const float* __restrict__ hin, const float* __restrict__ dinv,
                            float* __restrict__ hout, int N) {
    int idx = blockIdx.x * blockDim.x + threadIdx.x;
    if (idx < N * OUT_CH) {
        float d = dinv[idx >> 4];
        hout[idx] = d * d * hin[idx];
    }
}
__global__ void fb_scat(const int* __restrict__ row, const int* __restrict__ col,
                        const float* __restrict__ ew, const float* __restrict__ dinv,
                        const float* __restrict__ hin, float* __restrict__ hout, int E) {
    long long idx = (long long)blockIdx.x * blockDim.x + threadIdx.x;
    int e = (int)(idx >> 4);
    int c = (int)(idx & 15);
    if (e >= E) return;
    int r = row[e], cl = col[e];
    float nv = dinv[r] * ew[e] * dinv[cl];
    atomicAdd(&hout[(size_t)cl * OUT_CH + c], nv * hin[(size_t)r * OUT_CH + c]);
}
__global__ void fb_lsm(const float* __restrict__ h, float* __restrict__ out, int N) {
    int n = blockIdx.x * blockDim.x + threadIdx.x;
    if (n >= N) return;
    const float* hr = h + (size_t)n * OUT_CH;
    float v[OUT_CH];
#pragma unroll
    for (int i = 0; i < OUT_CH; i++) v[i] = hr[i];
    float m = v[0];
#pragma unroll
    for (int i = 1; i < OUT_CH; i++) m = fmaxf(m, v[i]);
    float s = 0.0f;
#pragma unroll
    for (int i = 0; i < OUT_CH; i++) s += expf(v[i] - m);
    float lse = m + logf(s);
    float* orow = out + (size_t)n * OUT_CH;
#pragma unroll
    for (int i = 0; i < OUT_CH; i++) orow[i] = v[i] - lse;
}

// ================= launch =================

extern "C" void kernel_launch(void* const* d_in, const int* in_sizes, int n_in,
                              void* d_out, int out_size, void* d_ws, size_t ws_size,
                              hipStream_t stream) {
    const float* x  = (const float*)d_in[0];
    const float* W  = (const float*)d_in[1];
    const float* ew = (const float*)d_in[2];
    const int*   ei = (const int*)d_in[3];  // harness pushes int64 as int32

    int N = in_sizes[0] / IN_CH;
    int E = in_sizes[2];
    const int* row = ei;       // source
    const int* col = ei + E;   // target

    auto al = [](size_t v) { return (v + 255) & ~(size_t)255; };
    size_t N16 = (size_t)N * OUT_CH;

    int NL = (N + LNODES - 1) >> LSH;
    int G  = (E + CH - 1) / CH;
    int gH = (int)((N16 + B - 1) / B);

    char* ws = (char*)d_ws;
    bool shape_ok = (NL <= MAXNL && G <= MAXG && N <= MAXNL * LNODES);

    // ---- cooperative megakernel path (no aliasing) ----
    size_t c_rec2 = 0;
    size_t c_rec  = c_rec2 + al((size_t)E * 8);
    size_t c_bh   = c_rec  + al((size_t)E * 8);
    size_t c_tot  = c_bh   + al((size_t)G * NL * 4);
    size_t c_nptr = c_tot  + al((size_t)NL * 4);
    size_t c_dinv = c_nptr + al((size_t)(N + 1) * 4);
    size_t c_g0   = c_dinv + al((size_t)N * 4);
    size_t c_g1   = c_g0   + al(N16 * 4);
    size_t c_need = c_g1   + al(N16 * 4);

    if (shape_ok && c_need <= ws_size) {
        MegaArgs a;
        a.row = row; a.col = col; a.ew = ew; a.x = x; a.W = W;
        a.rec2 = (uint2*)(ws + c_rec2);
        a.rec  = (uint2*)(ws + c_rec);
        a.bh   = (unsigned*)(ws + c_bh);
        a.tot  = (unsigned*)(ws + c_tot);
        a.nptr = (unsigned*)(ws + c_nptr);
        a.dinv = (float*)(ws + c_dinv);
        a.g0   = (float*)(ws + c_g0);
        a.g1   = (float*)(ws + c_g1);
        a.out  = (float*)d_out;
        a.N = N; a.E = E; a.G = G; a.NL = NL;

        int maxB = 0;
        hipError_t e1 = hipOccupancyMaxActiveBlocksPerMultiprocessor(
            &maxB, reinterpret_cast<const void*>(&mega), B, 0);
        int dev = 0, cus = 0;
        hipGetDevice(&dev);
        hipDeviceGetAttribute(&cus, hipDeviceAttributeMultiprocessorCount, dev);
        if (e1 == hipSuccess && maxB > 0 && cus > 0) {
            int grid = maxB * cus;
            int maxwork = G > NL ? G : NL;
            if (gH > maxwork) maxwork = gH;
            if (grid > maxwork) grid = maxwork;
            void* params[] = { (void*)&a };
            hipError_t e2 = hipLaunchCooperativeKernel(
                reinterpret_cast<const void*>(&mega), dim3(grid), dim3(B), params, 0, stream);
            if (e2 == hipSuccess) return;
        }
        // else: fall through to multi-kernel path
    }

    // ---- 7-kernel path (aliased layout, proven r9) ----
    size_t o_rec2 = 0;
    size_t o_rec  = o_rec2 + al((size_t)E * 8);
    size_t o_tot  = o_rec  + al((size_t)E * 8);
    size_t o_nptr = o_tot  + al((size_t)NL * 4);
    size_t o_dinv = o_nptr + al((size_t)(N + 1) * 4);
    size_t need   = o_dinv + al((size_t)N * 4);
    bool bh_fits = ((size_t)G * NL * 4 <= al((size_t)E * 8));   // bh aliases rec2
    bool g_fits  = (2 * al(N16 * 4) <= al((size_t)E * 8));      // g0+g1 alias rec

    if (shape_ok && bh_fits && g_fits && need <= ws_size) {
        uint2*    rec2 = (uint2*)(ws + o_rec2);
        unsigned* bh   = (unsigned*)(ws + o_rec2);   // dead before rec2 written
        uint2*    rec  = (uint2*)(ws + o_rec);
        float*    g0   = (float*)(ws + o_rec);       // written after rec dead
        float*    g1   = (float*)(ws + o_rec + al(N16 * 4));
        unsigned* tot  = (unsigned*)(ws + o_tot);
        unsigned* nptr = (unsigned*)(ws + o_nptr);
        float*    dinv = (float*)(ws + o_dinv);

        k_hist   <<<G,  B, 0, stream>>>(col, bh, E, NL);
        k_colscan<<<NL, B, 0, stream>>>(bh, tot, G, NL);
        k_place  <<<G,  B, 0, stream>>>(row, col, ew, bh, tot, rec, E, NL);
        k_sort2  <<<NL, B, 0, stream>>>(rec, tot, rec2, nptr, dinv, N, NL);
        k_proj   <<<(N + 15) / 16, B, 0, stream>>>(x, W, dinv, g0, N);
        k_hop<false><<<gH, B, 0, stream>>>(rec2, nptr, dinv, g0, g1, N);
        k_hop<true ><<<gH, B, 0, stream>>>(rec2, nptr, dinv, g1, (float*)d_out, N);
    } else {
        // ---- ultimate fallback (r2-style, ~6.8 MB ws) ----
        size_t f_deg  = 0;
        size_t f_dinv = f_deg  + al((size_t)N * 4);
        size_t f_h0   = f_dinv + al((size_t)N * 4);
        size_t f_h1   = f_h0   + al(N16 * 4);
        float* deg  = (float*)(ws + f_deg);
        float* dinv = (float*)(ws + f_dinv);
        float* h0   = (float*)(ws + f_h0);
        float* h1   = (float*)(ws + f_h1);

        int gN   = (N + B - 1) / B;
        int gE   = (E + B - 1) / B;
        int gN16 = (N * OUT_CH + B - 1) / B;
        long long scat = (long long)E * OUT_CH;
        int gScat = (int)((scat + B - 1) / B);

        fb_deginit<<<gN, B, 0, stream>>>(deg, N);
        fb_deg<<<gE, B, 0, stream>>>(col, ew, deg, E);
        fb_dinv<<<gN, B, 0, stream>>>(deg, dinv, N);
        fb_proj<<<(N + 15) / 16, B, 0, stream>>>(x, W, h0, N);
        float* hin = h0; float* hout = h1;
        for (int k = 0; k < 2; k++) {
            fb_selfinit<<<gN16, B, 0, stream>>>(hin, dinv, hout, N);
            fb_scat<<<gScat, B, 0, stream>>>(row, col, ew, dinv, hin, hout, E);
            float* t = hin; hin = hout; hout = t;
        }
        fb_lsm<<<gN, B, 0, stream>>>(hin, (float*)d_out, N);
    }
}

// Round 11
// 128.285 us; speedup vs baseline: 4.2430x; 4.2430x over previous
//
#include <hip/hip_runtime.h>
#include <math.h>

#define IN_CH 128
#define OUT_CH 16
#define B 256
#define CH_H 2048         // edges per histogram chunk
#define CH_P 4096         // edges per placement chunk (F = CH_P/CH_H = 2)
#define LSH 6             // leaf = node >> 6  (64 nodes per leaf)
#define LNODES 64
#define MAXNL 1024
#define MAXGH 2048

// exclusive prefix of vals[0..NL) into dst (LDS), B threads, 4 bins/thread
__device__ __forceinline__ void scan_nl(const unsigned* __restrict__ vals, unsigned* dst,
                                        unsigned* sums, int NL) {
    int tid = threadIdx.x;
    int b0 = tid * 4;
    unsigned v[4]; unsigned loc = 0;
#pragma unroll
    for (int q = 0; q < 4; ++q) { int i = b0 + q; v[q] = (i < NL) ? vals[i] : 0u; loc += v[q]; }
    sums[tid] = loc;
    __syncthreads();
    for (int off = 1; off < B; off <<= 1) {
        unsigned a = (tid >= off) ? sums[tid - off] : 0u;
        __syncthreads();
        sums[tid] += a;
        __syncthreads();
    }
    unsigned run = sums[tid] - loc;
#pragma unroll
    for (int q = 0; q < 4; ++q) { int i = b0 + q; if (i < NL) dst[i] = run; run += v[q]; }
    __syncthreads();
}

// --- per-chunk leaf histogram (CH_H edges/block, 3 blocks/CU for LDS-atomic balance) ---
__global__ void __launch_bounds__(B) k_hist(const int* __restrict__ col,
                                            unsigned* __restrict__ bh, int E, int NL) {
    __shared__ unsigned hc[MAXNL];
    int tid = threadIdx.x;
    for (int i = tid; i < NL; i += B) hc[i] = 0u;
    __syncthreads();
    int base = blockIdx.x * CH_H;
    int end = base + CH_H < E ? base + CH_H : E;
    for (int e = base + tid; e < end; e += B)
        atomicAdd(&hc[col[e] >> LSH], 1u);
    __syncthreads();
    unsigned* out = bh + (size_t)blockIdx.x * NL;
    for (int i = tid; i < NL; i += B) out[i] = hc[i];
}

// --- per-leaf exclusive scan over chunks (loops over G with carry); totals out ---
__global__ void __launch_bounds__(B) k_colscan(unsigned* __restrict__ bh,
                                               unsigned* __restrict__ tot, int G, int NL) {
    int j = blockIdx.x;
    __shared__ unsigned s[B];
    int tid = threadIdx.x;
    unsigned carry = 0;
    for (int g0 = 0; g0 < G; g0 += B) {
        __syncthreads();
        int g = g0 + tid;
        unsigned v = (g < G) ? bh[(size_t)g * NL + j] : 0u;
        s[tid] = v;
        __syncthreads();
        for (int off = 1; off < B; off <<= 1) {
            unsigned add = (tid >= off) ? s[tid - off] : 0u;
            __syncthreads();
            s[tid] += add;
            __syncthreads();
        }
        if (g < G) bh[(size_t)g * NL + j] = carry + s[tid] - v;
        carry += s[B - 1];
    }
    if (tid == 0) tot[j] = carry;
}

// --- placement: LDS counting sort by leaf, records staged in LDS, coalesced IO both ways ---
__global__ void __launch_bounds__(B)
k_place(const int* __restrict__ row, const int* __restrict__ col, const float* __restrict__ ew,
        const unsigned* __restrict__ bh, const unsigned* __restrict__ tot,
        uint2* __restrict__ rec, int E, int NL, int F) {
    __shared__ uint2 srec[CH_P];                    // 32 KB
    __shared__ unsigned short slf[CH_P];            // 8 KB
    __shared__ unsigned gbase[MAXNL];
    __shared__ unsigned lscan[MAXNL];
    __shared__ unsigned lctr[MAXNL];
    __shared__ unsigned sums[B];
    int tid = threadIdx.x;
    int c = blockIdx.x;
    int base = c * CH_P;
    int end = base + CH_P < E ? base + CH_P : E;
    int cnt = end - base;

    scan_nl(tot, gbase, sums, NL);                  // global leaf bases
    for (int i = tid; i < NL; i += B) lctr[i] = 0u;
    __syncthreads();
    for (int j = tid; j < cnt; j += B)
        atomicAdd(&lctr[col[base + j] >> LSH], 1u);
    __syncthreads();
    scan_nl(lctr, lscan, sums, NL);                 // local chunk bases
    for (int i = tid; i < NL; i += B) lctr[i] = lscan[i];
    __syncthreads();
    // build records at sorted LDS position (coalesced global reads)
    for (int j = tid; j < cnt; j += B) {
        int e = base + j;
        int cc = col[e];
        int lf = cc >> LSH;
        unsigned pos = atomicAdd(&lctr[lf], 1u);
        srec[pos] = make_uint2(((unsigned)row[e] << 6) | (unsigned)(cc & (LNODES - 1)),
                               __float_as_uint(ew[e]));
        slf[pos] = (unsigned short)lf;
    }
    __syncthreads();
    // stream LDS -> global (run-coalesced)
    const unsigned* myb = bh + (size_t)(c * F) * NL;
    for (int j = tid; j < cnt; j += B) {
        int lf = slf[j];
        unsigned outp = gbase[lf] + myb[lf] + ((unsigned)j - lscan[lf]);
        rec[outp] = srec[j];
    }
}

// --- second-level sort (by node within leaf): rec2 = {row, raw w}, nodeptr ---
__global__ void __launch_bounds__(B)
k_sort2(const uint2* __restrict__ rec, const unsigned* __restrict__ tot,
        uint2* __restrict__ rec2, unsigned* __restrict__ nptr, int N, int NL) {
    __shared__ unsigned sums[B];
    __shared__ unsigned gbase[MAXNL];
    __shared__ unsigned hist[LNODES];
    __shared__ unsigned start[LNODES];
    int l = blockIdx.x, tid = threadIdx.x;
    scan_nl(tot, gbase, sums, NL);
    int seg = (int)gbase[l];
    int end = seg + (int)tot[l];
    if (tid < LNODES) hist[tid] = 0u;
    __syncthreads();
    for (int j = seg + tid; j < end; j += B)
        atomicAdd(&hist[rec[j].x & (LNODES - 1)], 1u);
    __syncthreads();
    if (tid < LNODES) {  // one wave -> shfl scan
        unsigned v = hist[tid];
        unsigned sum = v;
        for (int off = 1; off < LNODES; off <<= 1) {
            unsigned o = __shfl_up(sum, off, 64);
            if (tid >= off) sum += o;
        }
        unsigned st = (unsigned)seg + sum - v;  // exclusive
        start[tid] = st;
        int n = l * LNODES + tid;
        if (n < N) nptr[n] = st;
    }
    if (l == NL - 1 && tid == 0) nptr[N] = (unsigned)end;
    __syncthreads();
    for (int j = seg + tid; j < end; j += B) {
        uint2 u = rec[j];
        unsigned pos = atomicAdd(&start[u.x & (LNODES - 1)], 1u);
        rec2[pos] = make_uint2(u.x >> 6, u.y);
    }
}

// --- projection + degree: dinv[n] from rec2 run; g0 = dinv ⊙ (x @ W^T) ---
__global__ void __launch_bounds__(B)
k_proj(const float* __restrict__ x, const float* __restrict__ W,
       const uint2* __restrict__ rec2, const unsigned* __restrict__ nptr,
       float* __restrict__ dinv, float* __restrict__ y, int N) {
    __shared__ float sW[OUT_CH * 132];
    int tid = threadIdx.x;
    for (int i = tid; i < OUT_CH * IN_CH; i += B) {
        int o = i >> 7, k = i & 127;
        sW[o * 132 + k] = W[i];
    }
    __syncthreads();
    int n = blockIdx.x * 16 + (tid >> 4);
    int o = tid & 15;
    if (n >= N) return;
    int j0 = (int)nptr[n], j1 = (int)nptr[n + 1];
    float wsum = 0.f;
    for (int j = j0 + o; j < j1; j += 16) wsum += __uint_as_float(rec2[j].y);
#pragma unroll
    for (int off = 1; off < 16; off <<= 1) wsum += __shfl_xor(wsum, off, 16);
    float dn = rsqrtf(1.0f + wsum);
    const float* xr = x + (size_t)n * IN_CH;
    const float* wr = sW + o * 132;
    float acc = 0.0f;
#pragma unroll
    for (int k = 0; k < IN_CH; k += 4) {
        float4 xv = *reinterpret_cast<const float4*>(xr + k);
        float4 wv = *reinterpret_cast<const float4*>(wr + k);
        acc += xv.x * wv.x + xv.y * wv.y + xv.z * wv.z + xv.w * wv.w;
    }
    y[(size_t)n * OUT_CH + o] = dn * acc;
    if (o == 0) dinv[n] = dn;
}

// --- CSR hop in g-space: 16 threads/node, register accumulation, no atomics ---
template <bool FINAL>
__global__ void __launch_bounds__(B)
k_hop(const uint2* __restrict__ rec2, const unsigned* __restrict__ nptr,
      const float* __restrict__ dinv, const float* __restrict__ gin,
      float* __restrict__ out, int N) {
    int t = blockIdx.x * B + threadIdx.x;
    int n = t >> 4, ch = t & 15;
    if (n >= N) return;
    int j0 = (int)nptr[n], j1 = (int)nptr[n + 1];
    float acc = 0.f;
    int j = j0;
    for (; j + 3 < j1; j += 4) {  // 4-wide for MLP
        uint2 u0 = rec2[j], u1 = rec2[j + 1], u2 = rec2[j + 2], u3 = rec2[j + 3];
        acc += __uint_as_float(u0.y) * gin[(size_t)u0.x * OUT_CH + ch]
             + __uint_as_float(u1.y) * gin[(size_t)u1.x * OUT_CH + ch]
             + __uint_as_float(u2.y) * gin[(size_t)u2.x * OUT_CH + ch]
             + __uint_as_float(u3.y) * gin[(size_t)u3.x * OUT_CH + ch];
    }
    for (; j < j1; ++j) {
        uint2 u = rec2[j];
        acc += __uint_as_float(u.y) * gin[(size_t)u.x * OUT_CH + ch];
    }
    float d = dinv[n];
    float s = gin[(size_t)n * OUT_CH + ch] + acc;
    if (!FINAL) {
        out[(size_t)n * OUT_CH + ch] = d * d * s;
    } else {
        float v = d * s;
        float m = v;
#pragma unroll
        for (int off = 1; off < 16; off <<= 1) m = fmaxf(m, __shfl_xor(m, off, 16));
        float se = expf(v - m);
#pragma unroll
        for (int off = 1; off < 16; off <<= 1) se += __shfl_xor(se, off, 16);
        out[(size_t)n * OUT_CH + ch] = v - m - logf(se);
    }
}

// ================= fallback path (proven r2 structure) =================

__global__ void fb_deginit(float* deg, int N) {
    int i = blockIdx.x * blockDim.x + threadIdx.x;
    if (i < N) deg[i] = 1.0f;
}
__global__ void fb_deg(const int* __restrict__ col, const float* __restrict__ ew,
                       float* deg, int E) {
    int e = blockIdx.x * blockDim.x + threadIdx.x;
    if (e < E) atomicAdd(&deg[col[e]], ew[e]);
}
__global__ void fb_dinv(const float* __restrict__ deg, float* dinv, int N) {
    int i = blockIdx.x * blockDim.x + threadIdx.x;
    if (i < N) dinv[i] = rsqrtf(deg[i]);
}
__global__ void fb_proj(const float* __restrict__ x, const float* __restrict__ W,
                        float* __restrict__ y, int N) {
    __shared__ float sW[OUT_CH * 132];
    for (int i = threadIdx.x; i < OUT_CH * IN_CH; i += blockDim.x) {
        int o = i >> 7, k = i & 127;
        sW[o * 132 + k] = W[i];
    }
    __syncthreads();
    int t = threadIdx.x;
    int n = blockIdx.x * 16 + (t >> 4);
    int o = t & 15;
    if (n >= N) return;
    const float* xr = x + (size_t)n * IN_CH;
    const float* wr = sW + o * 132;
    float acc = 0.0f;
#pragma unroll
    for (int k = 0; k < IN_CH; k += 4) {
        float4 xv = *reinterpret_cast<const float4*>(xr + k);
        float4 wv = *reinterpret_cast<const float4*>(wr + k);
        acc += xv.x * wv.x + xv.y * wv.y + xv.z * wv.z + xv.w * wv.w;
    }
    y[(size_t)n * OUT_CH + o] = acc;
}
__global__ void fb_selfinit(const float* __restrict__ hin, const float* __restrict__ dinv,
                            float* __restrict__ hout, int N) {
    int idx = blockIdx.x * blockDim.x + threadIdx.x;
    if (idx < N * OUT_CH) {
        float d = dinv[idx >> 4];
        hout[idx] = d * d * hin[idx];
    }
}
__global__ void fb_scat(const int* __restrict__ row, const int* __restrict__ col,
                        const float* __restrict__ ew, const float* __restrict__ dinv,
                        const float* __restrict__ hin, float* __restrict__ hout, int E) {
    long long idx = (long long)blockIdx.x * blockDim.x + threadIdx.x;
    int e = (int)(idx >> 4);
    int c = (int)(idx & 15);
    if (e >= E) return;
    int r = row[e], cl = col[e];
    float nv = dinv[r] * ew[e] * dinv[cl];
    atomicAdd(&hout[(size_t)cl * OUT_CH + c], nv * hin[(size_t)r * OUT_CH + c]);
}
__global__ void fb_lsm(const float* __restrict__ h, float* __restrict__ out, int N) {
    int n = blockIdx.x * blockDim.x + threadIdx.x;
    if (n >= N) return;
    const float* hr = h + (size_t)n * OUT_CH;
    float v[OUT_CH];
#pragma unroll
    for (int i = 0; i < OUT_CH; i++) v[i] = hr[i];
    float m = v[0];
#pragma unroll
    for (int i = 1; i < OUT_CH; i++) m = fmaxf(m, v[i]);
    float s = 0.0f;
#pragma unroll
    for (int i = 0; i < OUT_CH; i++) s += expf(v[i] - m);
    float lse = m + logf(s);
    float* orow = out + (size_t)n * OUT_CH;
#pragma unroll
    for (int i = 0; i < OUT_CH; i++) orow[i] = v[i] - lse;
}

// ================= launch =================

extern "C" void kernel_launch(void* const* d_in, const int* in_sizes, int n_in,
                              void* d_out, int out_size, void* d_ws, size_t ws_size,
                              hipStream_t stream) {
    const float* x  = (const float*)d_in[0];
    const float* W  = (const float*)d_in[1];
    const float* ew = (const float*)d_in[2];
    const int*   ei = (const int*)d_in[3];  // harness pushes int64 as int32

    int N = in_sizes[0] / IN_CH;
    int E = in_sizes[2];
    const int* row = ei;       // source
    const int* col = ei + E;   // target

    auto al = [](size_t v) { return (v + 255) & ~(size_t)255; };
    size_t N16 = (size_t)N * OUT_CH;

    int NL  = (N + LNODES - 1) >> LSH;
    int G_H = (E + CH_H - 1) / CH_H;
    int G_P = (E + CH_P - 1) / CH_P;
    int F   = CH_P / CH_H;
    int gH  = (int)((N16 + B - 1) / B);

    // layout: rec2(∪bh) | rec(∪g0,g1) | tot | nodeptr | dinv
    size_t o_rec2 = 0;
    size_t o_rec  = o_rec2 + al((size_t)E * 8);
    size_t o_tot  = o_rec  + al((size_t)E * 8);
    size_t o_nptr = o_tot  + al((size_t)NL * 4);
    size_t o_dinv = o_nptr + al((size_t)(N + 1) * 4);
    size_t need   = o_dinv + al((size_t)N * 4);

    bool bh_fits = ((size_t)G_H * NL * 4 <= al((size_t)E * 8));  // bh aliases rec2
    bool g_fits  = (2 * al(N16 * 4) <= al((size_t)E * 8));       // g0+g1 alias rec
    bool shape_ok = (NL <= MAXNL && G_H <= MAXGH && N <= MAXNL * LNODES &&
                     (G_P * F) <= G_H + F);  // bh[c*F] valid for all place chunks

    char* ws = (char*)d_ws;

    if (shape_ok && bh_fits && g_fits && need <= ws_size) {
        uint2*    rec2 = (uint2*)(ws + o_rec2);
        unsigned* bh   = (unsigned*)(ws + o_rec2);   // dead before rec2 written (k_sort2)
        uint2*    rec  = (uint2*)(ws + o_rec);
        float*    g0   = (float*)(ws + o_rec);       // written after rec dead (k_proj)
        float*    g1   = (float*)(ws + o_rec + al(N16 * 4));
        unsigned* tot  = (unsigned*)(ws + o_tot);
        unsigned* nptr = (unsigned*)(ws + o_nptr);
        float*    dinv = (float*)(ws + o_dinv);

        k_hist   <<<G_H, B, 0, stream>>>(col, bh, E, NL);
        k_colscan<<<NL,  B, 0, stream>>>(bh, tot, G_H, NL);
        k_place  <<<G_P, B, 0, stream>>>(row, col, ew, bh, tot, rec, E, NL, F);
        k_sort2  <<<NL,  B, 0, stream>>>(rec, tot, rec2, nptr, N, NL);
        k_proj   <<<(N + 15) / 16, B, 0, stream>>>(x, W, rec2, nptr, dinv, g0, N);
        k_hop<false><<<gH, B, 0, stream>>>(rec2, nptr, dinv, g0, g1, N);
        k_hop<true ><<<gH, B, 0, stream>>>(rec2, nptr, dinv, g1, (float*)d_out, N);
    } else {
        // ---- fallback (r2-style, ~6.8 MB ws) ----
        size_t f_deg  = 0;
        size_t f_dinv = f_deg  + al((size_t)N * 4);
        size_t f_h0   = f_dinv + al((size_t)N * 4);
        size_t f_h1   = f_h0   + al(N16 * 4);
        float* deg  = (float*)(ws + f_deg);
        float* dinv = (float*)(ws + f_dinv);
        float* h0   = (float*)(ws + f_h0);
        float* h1   = (float*)(ws + f_h1);

        int gN   = (N + B - 1) / B;
        int gE   = (E + B - 1) / B;
        int gN16 = (N * OUT_CH + B - 1) / B;
        long long scat = (long long)E * OUT_CH;
        int gScat = (int)((scat + B - 1) / B);

        fb_deginit<<<gN, B, 0, stream>>>(deg, N);
        fb_deg<<<gE, B, 0, stream>>>(col, ew, deg, E);
        fb_dinv<<<gN, B, 0, stream>>>(deg, dinv, N);
        fb_proj<<<(N + 15) / 16, B, 0, stream>>>(x, W, h0, N);
        float* hin = h0; float* hout = h1;
        for (int k = 0; k < 2; k++) {
            fb_selfinit<<<gN16, B, 0, stream>>>(hin, dinv, hout, N);
            fb_scat<<<gScat, B, 0, stream>>>(row, col, ew, dinv, hin, hout, E);
            float* t = hin; hin = hout; hout = t;
        }
        fb_lsm<<<gN, B, 0, stream>>>(hin, (float*)d_out, N);
    }
}

// Round 12
// 124.386 us; speedup vs baseline: 4.3760x; 1.0313x over previous
//
#include <hip/hip_runtime.h>
#include <hip/hip_fp16.h>
#include <math.h>

#define IN_CH 128
#define OUT_CH 16
#define B 256
#define CH_H 2048         // edges per histogram chunk
#define CH_P 4096         // edges per placement chunk (F = CH_P/CH_H = 2)
#define LSH 6             // leaf = node >> 6  (64 nodes per leaf)
#define LNODES 64
#define MAXNL 1024
#define MAXGH 2048

__device__ __forceinline__ unsigned short f2h(float f) {
    __half h = __float2half(f);
    unsigned short u;
    __builtin_memcpy(&u, &h, 2);
    return u;
}
__device__ __forceinline__ float h2f(unsigned short u) {
    __half h;
    __builtin_memcpy(&h, &u, 2);
    return __half2float(h);
}

// exclusive prefix of vals[0..NL) into dst (LDS), B threads, 4 bins/thread
__device__ __forceinline__ void scan_nl(const unsigned* __restrict__ vals, unsigned* dst,
                                        unsigned* sums, int NL) {
    int tid = threadIdx.x;
    int b0 = tid * 4;
    unsigned v[4]; unsigned loc = 0;
#pragma unroll
    for (int q = 0; q < 4; ++q) { int i = b0 + q; v[q] = (i < NL) ? vals[i] : 0u; loc += v[q]; }
    sums[tid] = loc;
    __syncthreads();
    for (int off = 1; off < B; off <<= 1) {
        unsigned a = (tid >= off) ? sums[tid - off] : 0u;
        __syncthreads();
        sums[tid] += a;
        __syncthreads();
    }
    unsigned run = sums[tid] - loc;
#pragma unroll
    for (int q = 0; q < 4; ++q) { int i = b0 + q; if (i < NL) dst[i] = run; run += v[q]; }
    __syncthreads();
}

// --- per-chunk leaf histogram ---
__global__ void __launch_bounds__(B) k_hist(const int* __restrict__ col,
                                            unsigned* __restrict__ bh, int E, int NL) {
    __shared__ unsigned hc[MAXNL];
    int tid = threadIdx.x;
    for (int i = tid; i < NL; i += B) hc[i] = 0u;
    __syncthreads();
    int base = blockIdx.x * CH_H;
    int end = base + CH_H < E ? base + CH_H : E;
    for (int e = base + tid; e < end; e += B)
        atomicAdd(&hc[col[e] >> LSH], 1u);
    __syncthreads();
    unsigned* out = bh + (size_t)blockIdx.x * NL;
    for (int i = tid; i < NL; i += B) out[i] = hc[i];
}

// --- per-leaf exclusive scan over chunks (loops over G with carry); totals out ---
__global__ void __launch_bounds__(B) k_colscan(unsigned* __restrict__ bh,
                                               unsigned* __restrict__ tot, int G, int NL) {
    int j = blockIdx.x;
    __shared__ unsigned s[B];
    int tid = threadIdx.x;
    unsigned carry = 0;
    for (int g0 = 0; g0 < G; g0 += B) {
        __syncthreads();
        int g = g0 + tid;
        unsigned v = (g < G) ? bh[(size_t)g * NL + j] : 0u;
        s[tid] = v;
        __syncthreads();
        for (int off = 1; off < B; off <<= 1) {
            unsigned add = (tid >= off) ? s[tid - off] : 0u;
            __syncthreads();
            s[tid] += add;
            __syncthreads();
        }
        if (g < G) bh[(size_t)g * NL + j] = carry + s[tid] - v;
        carry += s[B - 1];
    }
    if (tid == 0) tot[j] = carry;
}

// --- placement: LDS counting sort by leaf, records staged in LDS, coalesced IO both ways ---
__global__ void __launch_bounds__(B)
k_place(const int* __restrict__ row, const int* __restrict__ col, const float* __restrict__ ew,
        const unsigned* __restrict__ bh, const unsigned* __restrict__ tot,
        uint2* __restrict__ rec, int E, int NL, int F) {
    __shared__ uint2 srec[CH_P];                    // 32 KB
    __shared__ unsigned short slf[CH_P];            // 8 KB
    __shared__ unsigned gbase[MAXNL];
    __shared__ unsigned lscan[MAXNL];
    __shared__ unsigned lctr[MAXNL];
    __shared__ unsigned sums[B];
    int tid = threadIdx.x;
    int c = blockIdx.x;
    int base = c * CH_P;
    int end = base + CH_P < E ? base + CH_P : E;
    int cnt = end - base;

    scan_nl(tot, gbase, sums, NL);                  // global leaf bases
    for (int i = tid; i < NL; i += B) lctr[i] = 0u;
    __syncthreads();
    for (int j = tid; j < cnt; j += B)
        atomicAdd(&lctr[col[base + j] >> LSH], 1u);
    __syncthreads();
    scan_nl(lctr, lscan, sums, NL);                 // local chunk bases
    for (int i = tid; i < NL; i += B) lctr[i] = lscan[i];
    __syncthreads();
    for (int j = tid; j < cnt; j += B) {            // build records at sorted LDS position
        int e = base + j;
        int cc = col[e];
        int lf = cc >> LSH;
        unsigned pos = atomicAdd(&lctr[lf], 1u);
        srec[pos] = make_uint2(((unsigned)row[e] << 6) | (unsigned)(cc & (LNODES - 1)),
                               __float_as_uint(ew[e]));
        slf[pos] = (unsigned short)lf;
    }
    __syncthreads();
    const unsigned* myb = bh + (size_t)(c * F) * NL;
    for (int j = tid; j < cnt; j += B) {            // stream LDS -> global (run-coalesced)
        int lf = slf[j];
        unsigned outp = gbase[lf] + myb[lf] + ((unsigned)j - lscan[lf]);
        rec[outp] = srec[j];
    }
}

// --- fused: node-sort within leaf -> rec2{row16|f16 w}, nodeptr, dinv, and
//     the 64-node projection tile g0 = dinv * (x @ W^T) ---
__global__ void __launch_bounds__(B)
k_sort2proj(const uint2* __restrict__ rec, const unsigned* __restrict__ tot,
            const float* __restrict__ x, const float* __restrict__ W,
            unsigned* __restrict__ rec2, unsigned* __restrict__ nptr,
            float* __restrict__ dinv, float* __restrict__ g0, int N, int NL) {
    __shared__ unsigned sums[B];
    __shared__ unsigned gbase[MAXNL];
    __shared__ unsigned hist[LNODES];
    __shared__ unsigned start[LNODES];
    __shared__ float dacc[LNODES];
    __shared__ float dloc[LNODES];
    __shared__ float sW[OUT_CH * 132];
    int l = blockIdx.x, tid = threadIdx.x;

    for (int i = tid; i < OUT_CH * IN_CH; i += B) {   // stage W
        int o = i >> 7, k = i & 127;
        sW[o * 132 + k] = W[i];
    }
    scan_nl(tot, gbase, sums, NL);
    int seg = (int)gbase[l];
    int end = seg + (int)tot[l];
    if (tid < LNODES) { hist[tid] = 0u; dacc[tid] = 0.f; }
    __syncthreads();
    for (int j = seg + tid; j < end; j += B) {
        uint2 u = rec[j];
        int cc = (int)(u.x & (LNODES - 1));
        atomicAdd(&hist[cc], 1u);
        atomicAdd(&dacc[cc], __uint_as_float(u.y));    // exact f32 degree
    }
    __syncthreads();
    if (tid < LNODES) {  // one wave -> shfl scan
        unsigned v = hist[tid];
        unsigned sum = v;
        for (int off = 1; off < LNODES; off <<= 1) {
            unsigned o = __shfl_up(sum, off, 64);
            if (tid >= off) sum += o;
        }
        unsigned st = (unsigned)seg + sum - v;  // exclusive
        start[tid] = st;
        float dn = rsqrtf(1.0f + dacc[tid]);
        dloc[tid] = dn;
        int n = l * LNODES + tid;
        if (n < N) { nptr[n] = st; dinv[n] = dn; }
    }
    if (l == NL - 1 && tid == 0) nptr[N] = (unsigned)end;
    __syncthreads();
    for (int j = seg + tid; j < end; j += B) {         // scatter packed rec2
        uint2 u = rec[j];
        int cc = (int)(u.x & (LNODES - 1));
        unsigned pos = atomicAdd(&start[cc], 1u);
        rec2[pos] = ((u.x >> 6) << 16) | (unsigned)f2h(__uint_as_float(u.y));
    }
    // projection for this leaf's 64 nodes (independent of the scatter above)
    int o = tid & 15;
    for (int nl = tid >> 4; nl < LNODES; nl += 16) {
        int n = l * LNODES + nl;
        if (n >= N) break;
        const float* xr = x + (size_t)n * IN_CH;
        const float* wr = sW + o * 132;
        float acc = 0.0f;
#pragma unroll
        for (int k = 0; k < IN_CH; k += 4) {
            float4 xv = *reinterpret_cast<const float4*>(xr + k);
            float4 wv = *reinterpret_cast<const float4*>(wr + k);
            acc += xv.x * wv.x + xv.y * wv.y + xv.z * wv.z + xv.w * wv.w;
        }
        g0[(size_t)n * OUT_CH + o] = dloc[nl] * acc;
    }
}

// --- CSR hop in g-space: 16 threads/node, register accumulation, no atomics ---
template <bool FINAL>
__global__ void __launch_bounds__(B)
k_hop(const unsigned* __restrict__ rec2, const unsigned* __restrict__ nptr,
      const float* __restrict__ dinv, const float* __restrict__ gin,
      float* __restrict__ out, int N) {
    int t = blockIdx.x * B + threadIdx.x;
    int n = t >> 4, ch = t & 15;
    if (n >= N) return;
    int j0 = (int)nptr[n], j1 = (int)nptr[n + 1];
    float acc = 0.f;
    int j = j0;
    for (; j + 3 < j1; j += 4) {  // 4-wide for MLP
        unsigned u0 = rec2[j], u1 = rec2[j + 1], u2 = rec2[j + 2], u3 = rec2[j + 3];
        acc += h2f((unsigned short)u0) * gin[(size_t)(u0 >> 16) * OUT_CH + ch]
             + h2f((unsigned short)u1) * gin[(size_t)(u1 >> 16) * OUT_CH + ch]
             + h2f((unsigned short)u2) * gin[(size_t)(u2 >> 16) * OUT_CH + ch]
             + h2f((unsigned short)u3) * gin[(size_t)(u3 >> 16) * OUT_CH + ch];
    }
    for (; j < j1; ++j) {
        unsigned u = rec2[j];
        acc += h2f((unsigned short)u) * gin[(size_t)(u >> 16) * OUT_CH + ch];
    }
    float d = dinv[n];
    float s = gin[(size_t)n * OUT_CH + ch] + acc;
    if (!FINAL) {
        out[(size_t)n * OUT_CH + ch] = d * d * s;
    } else {
        float v = d * s;
        float m = v;
#pragma unroll
        for (int off = 1; off < 16; off <<= 1) m = fmaxf(m, __shfl_xor(m, off, 16));
        float se = expf(v - m);
#pragma unroll
        for (int off = 1; off < 16; off <<= 1) se += __shfl_xor(se, off, 16);
        out[(size_t)n * OUT_CH + ch] = v - m - logf(se);
    }
}

// ================= fallback path (proven r2 structure) =================

__global__ void fb_deginit(float* deg, int N) {
    int i = blockIdx.x * blockDim.x + threadIdx.x;
    if (i < N) deg[i] = 1.0f;
}
__global__ void fb_deg(const int* __restrict__ col, const float* __restrict__ ew,
                       float* deg, int E) {
    int e = blockIdx.x * blockDim.x + threadIdx.x;
    if (e < E) atomicAdd(&deg[col[e]], ew[e]);
}
__global__ void fb_dinv(const float* __restrict__ deg, float* dinv, int N) {
    int i = blockIdx.x * blockDim.x + threadIdx.x;
    if (i < N) dinv[i] = rsqrtf(deg[i]);
}
__global__ void fb_proj(const float* __restrict__ x, const float* __restrict__ W,
                        float* __restrict__ y, int N) {
    __shared__ float sW[OUT_CH * 132];
    for (int i = threadIdx.x; i < OUT_CH * IN_CH; i += blockDim.x) {
        int o = i >> 7, k = i & 127;
        sW[o * 132 + k] = W[i];
    }
    __syncthreads();
    int t = threadIdx.x;
    int n = blockIdx.x * 16 + (t >> 4);
    int o = t & 15;
    if (n >= N) return;
    const float* xr = x + (size_t)n * IN_CH;
    const float* wr = sW + o * 132;
    float acc = 0.0f;
#pragma unroll
    for (int k = 0; k < IN_CH; k += 4) {
        float4 xv = *reinterpret_cast<const float4*>(xr + k);
        float4 wv = *reinterpret_cast<const float4*>(wr + k);
        acc += xv.x * wv.x + xv.y * wv.y + xv.z * wv.z + xv.w * wv.w;
    }
    y[(size_t)n * OUT_CH + o] = acc;
}
__global__ void fb_selfinit(const float* __restrict__ hin, const float* __restrict__ dinv,
                            float* __restrict__ hout, int N) {
    int idx = blockIdx.x * blockDim.x + threadIdx.x;
    if (idx < N * OUT_CH) {
        float d = dinv[idx >> 4];
        hout[idx] = d * d * hin[idx];
    }
}
__global__ void fb_scat(const int* __restrict__ row, const int* __restrict__ col,
                        const float* __restrict__ ew, const float* __restrict__ dinv,
                        const float* __restrict__ hin, float* __restrict__ hout, int E) {
    long long idx = (long long)blockIdx.x * blockDim.x + threadIdx.x;
    int e = (int)(idx >> 4);
    int c = (int)(idx & 15);
    if (e >= E) return;
    int r = row[e], cl = col[e];
    float nv = dinv[r] * ew[e] * dinv[cl];
    atomicAdd(&hout[(size_t)cl * OUT_CH + c], nv * hin[(size_t)r * OUT_CH + c]);
}
__global__ void fb_lsm(const float* __restrict__ h, float* __restrict__ out, int N) {
    int n = blockIdx.x * blockDim.x + threadIdx.x;
    if (n >= N) return;
    const float* hr = h + (size_t)n * OUT_CH;
    float v[OUT_CH];
#pragma unroll
    for (int i = 0; i < OUT_CH; i++) v[i] = hr[i];
    float m = v[0];
#pragma unroll
    for (int i = 1; i < OUT_CH; i++) m = fmaxf(m, v[i]);
    float s = 0.0f;
#pragma unroll
    for (int i = 0; i < OUT_CH; i++) s += expf(v[i] - m);
    float lse = m + logf(s);
    float* orow = out + (size_t)n * OUT_CH;
#pragma unroll
    for (int i = 0; i < OUT_CH; i++) orow[i] = v[i] - lse;
}

// ================= launch =================

extern "C" void kernel_launch(void* const* d_in, const int* in_sizes, int n_in,
                              void* d_out, int out_size, void* d_ws, size_t ws_size,
                              hipStream_t stream) {
    const float* x  = (const float*)d_in[0];
    const float* W  = (const float*)d_in[1];
    const float* ew = (const float*)d_in[2];
    const int*   ei = (const int*)d_in[3];  // harness pushes int64 as int32

    int N = in_sizes[0] / IN_CH;
    int E = in_sizes[2];
    const int* row = ei;       // source
    const int* col = ei + E;   // target

    auto al = [](size_t v) { return (v + 255) & ~(size_t)255; };
    size_t N16 = (size_t)N * OUT_CH;

    int NL  = (N + LNODES - 1) >> LSH;
    int G_H = (E + CH_H - 1) / CH_H;
    int G_P = (E + CH_P - 1) / CH_P;
    int F   = CH_P / CH_H;
    int gH  = (int)((N16 + B - 1) / B);

    // plain sequential layout (ws is 256 MiB; no aliasing needed)
    size_t o_rec  = 0;
    size_t o_rec2 = o_rec  + al((size_t)E * 8);
    size_t o_bh   = o_rec2 + al((size_t)E * 4);
    size_t o_tot  = o_bh   + al((size_t)G_H * NL * 4);
    size_t o_nptr = o_tot  + al((size_t)NL * 4);
    size_t o_dinv = o_nptr + al((size_t)(N + 1) * 4);
    size_t o_g0   = o_dinv + al((size_t)N * 4);
    size_t o_g1   = o_g0   + al(N16 * 4);
    size_t need   = o_g1   + al(N16 * 4);

    bool shape_ok = (NL <= MAXNL && G_H <= MAXGH && N <= 65536 &&
                     (G_P * F) <= G_H + F);

    char* ws = (char*)d_ws;

    if (shape_ok && need <= ws_size) {
        uint2*    rec  = (uint2*)(ws + o_rec);
        unsigned* rec2 = (unsigned*)(ws + o_rec2);
        unsigned* bh   = (unsigned*)(ws + o_bh);
        unsigned* tot  = (unsigned*)(ws + o_tot);
        unsigned* nptr = (unsigned*)(ws + o_nptr);
        float*    dinv = (float*)(ws + o_dinv);
        float*    g0   = (float*)(ws + o_g0);
        float*    g1   = (float*)(ws + o_g1);

        k_hist     <<<G_H, B, 0, stream>>>(col, bh, E, NL);
        k_colscan  <<<NL,  B, 0, stream>>>(bh, tot, G_H, NL);
        k_place    <<<G_P, B, 0, stream>>>(row, col, ew, bh, tot, rec, E, NL, F);
        k_sort2proj<<<NL,  B, 0, stream>>>(rec, tot, x, W, rec2, nptr, dinv, g0, N, NL);
        k_hop<false><<<gH, B, 0, stream>>>(rec2, nptr, dinv, g0, g1, N);
        k_hop<true ><<<gH, B, 0, stream>>>(rec2, nptr, dinv, g1, (float*)d_out, N);
    } else {
        // ---- fallback (r2-style, ~6.8 MB ws) ----
        size_t f_deg  = 0;
        size_t f_dinv = f_deg  + al((size_t)N * 4);
        size_t f_h0   = f_dinv + al((size_t)N * 4);
        size_t f_h1   = f_h0   + al(N16 * 4);
        float* deg  = (float*)(ws + f_deg);
        float* dinv = (float*)(ws + f_dinv);
        float* h0   = (float*)(ws + f_h0);
        float* h1   = (float*)(ws + f_h1);

        int gN   = (N + B - 1) / B;
        int gE   = (E + B - 1) / B;
        int gN16 = (N * OUT_CH + B - 1) / B;
        long long scat = (long long)E * OUT_CH;
        int gScat = (int)((scat + B - 1) / B);

        fb_deginit<<<gN, B, 0, stream>>>(deg, N);
        fb_deg<<<gE, B, 0, stream>>>(col, ew, deg, E);
        fb_dinv<<<gN, B, 0, stream>>>(deg, dinv, N);
        fb_proj<<<(N + 15) / 16, B, 0, stream>>>(x, W, h0, N);
        float* hin = h0; float* hout = h1;
        for (int k = 0; k < 2; k++) {
            fb_selfinit<<<gN16, B, 0, stream>>>(hin, dinv, hout, N);
            fb_scat<<<gScat, B, 0, stream>>>(row, col, ew, dinv, hin, hout, E);
            float* t = hin; hin = hout; hout = t;
        }
        fb_lsm<<<gN, B, 0, stream>>>(hin, (float*)d_out, N);
    }
}